// Round 18
// baseline (175.123 us; speedup 1.0000x reference)
//
#include <hip/hip_runtime.h>
#include <math.h>

// Problem constants (fixed by setup_inputs): B=4, L=4096, k=16, PE_DIM=64.
// d_out is a FLOAT32 buffer; harness bf16-quantizes both sides for compare.
namespace {
constexpr int BB  = 4;
constexpr int LL  = 4096;
constexpr int KK  = 16;
constexpr int NF  = 16;
constexpr int GRID = 64;               // 64x64 cells, h=8
constexpr int NCELL = GRID * GRID;     // 4096
constexpr float WORLD_LO = -256.0f, CELL_INV = 0.125f;
constexpr int RMAX = 6;
constexpr unsigned TARGET = 48;        // ring candidate target (incl. self)
constexpr int CAP = 768;               // LDS staged-candidate cap

// d_ws layout (u32): per batch stride 6208 = cell_start[4097] pad + sidx u16[4096];
// then hard_cnt[1] + hard_list[1024]. Total 103428 B <= 131072 (proven R11).
constexpr int WSB_U32   = 6208;
constexpr int SIDX_OFF  = 4104;
constexpr int HARD_CNT  = BB * WSB_U32;      // 24832
constexpr int HARD_LIST = HARD_CNT + 1;      // 24833
constexpr int HARD_CAP  = 1024;

constexpr size_t N_IDX    = (size_t)BB * LL * KK;                 // 262144
constexpr size_t OFF_RPE  = N_IDX;
constexpr size_t OFF_SELF = OFF_RPE + N_IDX * 64;                 // 17039360
constexpr size_t OFF_DIST = OFF_SELF + (size_t)BB * LL * 64;      // 18087936
constexpr size_t OFF_NPOS = OFF_DIST + N_IDX;                     // 18350080
}

__device__ __forceinline__ float bf16r(float x) {
  unsigned u = __float_as_uint(x);
  unsigned r = (u + 0x7FFFu + ((u >> 16) & 1u)) & 0xFFFF0000u;
  return __uint_as_float(r);
}

// XLA-exact squared distance: rn(dx*dx) + rn(dy*dy), no fma contraction
__device__ __forceinline__ float d2_of(float cx, float cy, float px, float py) {
  const float dx = cx - px, dy = cy - py;
  return __fadd_rn(__fmul_rn(dx, dx), __fmul_rn(dy, dy));
}

// 16-deep predicated bubble insert (static indices only)
__device__ __forceinline__ void insert16(unsigned long long (&key)[KK],
                                         unsigned long long kj) {
  #pragma unroll
  for (int t = 0; t < KK; ++t) {
    const bool lt = kj < key[t];
    const unsigned long long nk = lt ? kj : key[t];
    const unsigned long long ok = lt ? key[t] : kj;
    key[t] = nk; kj = ok;
  }
}

// merge 32 per-lane sorted lists (half-wave); writes 16 results; returns 16th.
__device__ __forceinline__ unsigned long long
merge_write32(unsigned long long (&key)[KK], float* __restrict__ out, size_t g3) {
  unsigned long long last = ~0ULL;
  #pragma unroll
  for (int r = 0; r < KK; ++r) {
    unsigned long long m = key[0];
    #pragma unroll
    for (int off = 16; off; off >>= 1) {
      const unsigned long long o = __shfl_xor(m, off, 32);
      m = (o < m) ? o : m;
    }
    if (key[0] == m) {
      out[g3 * KK + r] = (float)(unsigned)(m & 0xFFFFFFFFu);
      #pragma unroll
      for (int j = 0; j < KK - 1; ++j) key[j] = key[j + 1];
      key[KK - 1] = ~0ULL;
    }
    last = m;
  }
  return last;
}

// ---- Kernel B: counting sort + position reorder (one block/batch) ----
__global__ __launch_bounds__(256)
void bin_kernel(const float* __restrict__ positions,
                unsigned* __restrict__ ws,
                float* __restrict__ out)
{
  __shared__ unsigned cnt[NCELL];            // 16 KB
  __shared__ unsigned wsum[4];
  const int tid = threadIdx.x, b = blockIdx.x;
  const float2* p2 = (const float2*)positions + (size_t)b * LL;
  unsigned* cs = ws + (size_t)b * WSB_U32;
  unsigned short* sidx = (unsigned short*)(cs + SIDX_OFF);
  float2* posw = (float2*)(out + OFF_RPE) + (size_t)b * LL;   // temp stash

  if (b == 0 && tid == 0) ws[HARD_CNT] = 0u;

  #pragma unroll
  for (int j = 0; j < NCELL / 256; ++j) cnt[tid + j * 256] = 0u;
  __syncthreads();

  int cellv[LL / 256];                       // 16 cells/thread, static idx
  #pragma unroll
  for (int j = 0; j < LL / 256; ++j) {
    const int pi = tid + j * 256;
    const float2 p = p2[pi];
    int cx = (int)floorf((p.x - WORLD_LO) * CELL_INV);
    int cy = (int)floorf((p.y - WORLD_LO) * CELL_INV);
    cx = min(max(cx, 0), GRID - 1);
    cy = min(max(cy, 0), GRID - 1);
    cellv[j] = cy * GRID + cx;
    atomicAdd(&cnt[cellv[j]], 1u);
  }
  __syncthreads();

  unsigned csum = 0;                         // 16-cell chunk sum
  #pragma unroll
  for (int k = 0; k < 16; ++k) csum += cnt[tid * 16 + k];
  unsigned inc = csum;                       // wave-64 inclusive scan
  #pragma unroll
  for (int off = 1; off < 64; off <<= 1) {
    const unsigned y = __shfl_up(inc, off, 64);
    if ((tid & 63) >= off) inc += y;
  }
  if ((tid & 63) == 63) wsum[tid >> 6] = inc;
  __syncthreads();
  const int w = tid >> 6;
  const unsigned w0 = wsum[0], w1 = wsum[1], w2 = wsum[2];
  const unsigned woff = (w > 0 ? w0 : 0u) + (w > 1 ? w1 : 0u) + (w > 2 ? w2 : 0u);
  unsigned run = woff + inc - csum;          // exclusive chunk base
  #pragma unroll
  for (int k = 0; k < 16; ++k) {             // in-place: counts -> starts
    const unsigned v = cnt[tid * 16 + k];
    cnt[tid * 16 + k] = run;
    cs[tid * 16 + k] = run;
    run += v;
  }
  if (tid == 255) cs[NCELL] = (unsigned)LL;
  __syncthreads();

  #pragma unroll
  for (int j = 0; j < LL / 256; ++j) {       // scatter idx + position
    const int pi = tid + j * 256;
    const float2 p = p2[pi];
    const unsigned slot = atomicAdd(&cnt[cellv[j]], 1u);
    sidx[slot] = (unsigned short)pi;
    posw[slot] = p;
  }
}

// ---- Kernel C: one block per cell; LDS-staged ring; half-wave per query ----
__global__ __launch_bounds__(256)
void cell_kernel(const float* __restrict__ positions,
                 unsigned* __restrict__ ws,
                 float* __restrict__ out)
{
  __shared__ float2 spos[CAP];               // 6 KB
  __shared__ unsigned short sid[CAP];        // 1.5 KB
  const int tid = threadIdx.x;
  const int b = blockIdx.x >> 12, cell = blockIdx.x & 4095;
  unsigned* cs = ws + (size_t)b * WSB_U32;
  const unsigned short* sidx = (const unsigned short*)(cs + SIDX_OFF);
  const float2* posw = (const float2*)(out + OFF_RPE) + (size_t)b * LL;
  const float2* p2 = (const float2*)positions + (size_t)b * LL;

  const unsigned qa = cs[cell], qe = cs[cell + 1];
  const int nq = (int)(qe - qa);
  if (nq == 0) return;
  const int cx = cell & (GRID - 1), cy = cell >> 6;

  // adaptive ring: smallest Rs with count >= TARGET (uniform across block)
  int Rs = RMAX; unsigned tot = 0; bool found = false;
  for (int R = 1; R <= RMAX && !found; ++R) {
    const int ay0 = max(cy - R, 0), ay1 = min(cy + R, GRID - 1);
    const int ax0 = max(cx - R, 0), ax1 = min(cx + R, GRID - 1);
    unsigned t = 0;
    for (int row = ay0; row <= ay1; ++row)
      t += cs[row * GRID + ax1 + 1] - cs[row * GRID + ax0];
    Rs = R; tot = t;
    if (t >= TARGET) found = true;
  }
  const bool cellhard = (!found) || (tot > (unsigned)CAP) || (tot < 17u);

  const int ry0 = max(cy - Rs, 0), ry1 = min(cy + Rs, GRID - 1);
  const int rx0 = max(cx - Rs, 0), rx1 = min(cx + Rs, GRID - 1);
  if (!cellhard) {                           // stage ring: coalesced spans
    unsigned off = 0;
    for (int row = ry0; row <= ry1; ++row) {
      const unsigned a = cs[row * GRID + rx0];
      const unsigned e = cs[row * GRID + rx1 + 1];
      const unsigned len = e - a;
      for (unsigned j = tid; j < len; j += 256) {
        spos[off + j] = posw[a + j];
        sid[off + j]  = sidx[a + j];
      }
      off += len;
    }
  }
  __syncthreads();

  const int s = tid & 31, hw = tid >> 5;
  const float bound = (float)(Rs * 8 * Rs * 8);   // exact small int in f32

  for (int qi = hw; qi < nq; qi += 8) {
    const int qrow = (int)sidx[qa + qi];
    const float2 P = posw[qa + qi];
    const size_t g3 = (size_t)b * LL + qrow;
    bool needhard = cellhard;

    if (!cellhard) {
      unsigned long long key[KK];
      #pragma unroll
      for (int j = 0; j < KK; ++j) key[j] = ~0ULL;
      const int iters = ((int)tot + 31) / 32;
      for (int i = 0; i < iters; ++i) {
        const int j = s + i * 32;
        if (j < (int)tot) {
          const float2 c = spos[j];
          const float d2 = d2_of(c.x, c.y, P.x, P.y);
          const int ci = (int)sid[j];
          if (ci != qrow) {
            const unsigned long long kj =
                ((unsigned long long)__float_as_uint(d2) << 32) | (unsigned)ci;
            if (kj < key[KK - 1]) insert16(key, kj);
          }
        }
      }
      const unsigned long long kth = merge_write32(key, out, g3);
      const float kd = __uint_as_float((unsigned)(kth >> 32));
      // certified: unexplored cells all >= Rs*8 away -> d2 >= bound > kth
      needhard = !(kd < bound);
    }

    if (needhard) {
      unsigned slot = 0;
      if (s == 0) slot = atomicAdd(&ws[HARD_CNT], 1u);
      slot = __shfl(slot, 0, 32);
      if (s == 0 && slot < (unsigned)HARD_CAP)
        ws[HARD_LIST + slot] = ((unsigned)b << 12) | (unsigned)qrow;
      if (slot >= (unsigned)HARD_CAP) {
        // overflow (p~0): inline exhaustive, half-wave (R16-proven)
        unsigned long long key[KK];
        #pragma unroll
        for (int j = 0; j < KK; ++j) key[j] = ~0ULL;
        unsigned dmax = 0xFFFFFFFFu;
        for (int i = 0; i < LL / 32; ++i) {
          const int ci = s + i * 32;
          const float2 c = p2[ci];
          const float d2 = d2_of(c.x, c.y, P.x, P.y);
          const unsigned d2b = __float_as_uint(d2);
          if (d2b < dmax && ci != qrow) {
            insert16(key, ((unsigned long long)d2b << 32) | (unsigned)ci);
            dmax = (unsigned)(key[KK - 1] >> 32);
          }
        }
        merge_write32(key, out, g3);
      }
    }
  }
}

// ---- Kernel H: one block per hard query; exhaustive exact top-16 ----
__global__ __launch_bounds__(256)
void hard_kernel(const float* __restrict__ positions,
                 const unsigned* __restrict__ ws,
                 float* __restrict__ out)
{
  __shared__ unsigned long long wres[4 * KK];
  const unsigned cntr = ws[HARD_CNT];
  const unsigned n = cntr < (unsigned)HARD_CAP ? cntr : (unsigned)HARD_CAP;
  if (blockIdx.x >= n) return;
  const unsigned enc = ws[HARD_LIST + blockIdx.x];
  const int b = (int)(enc >> 12), qrow = (int)(enc & 4095);
  const float2* p2 = (const float2*)positions + (size_t)b * LL;
  const float2 P = p2[qrow];
  const int tid = threadIdx.x, w = tid >> 6, lane = tid & 63;
  const size_t g3 = (size_t)b * LL + qrow;

  unsigned long long key[KK];
  #pragma unroll
  for (int j = 0; j < KK; ++j) key[j] = ~0ULL;
  #pragma unroll
  for (int i = 0; i < KK; ++i) {             // 16 coalesced candidates/thread
    const int ci = tid + i * 256;
    const float2 c = p2[ci];
    const float d2 = d2_of(c.x, c.y, P.x, P.y);
    if (ci != qrow)
      insert16(key, ((unsigned long long)__float_as_uint(d2) << 32) |
                    (unsigned)ci);
  }
  // per-wave width-64 merge -> wres[w][0..15] sorted
  #pragma unroll
  for (int r = 0; r < KK; ++r) {
    unsigned long long m = key[0];
    #pragma unroll
    for (int off = 32; off; off >>= 1) {
      const unsigned long long o = __shfl_xor(m, off, 64);
      m = (o < m) ? o : m;
    }
    if (key[0] == m) {                       // unique winner pops
      #pragma unroll
      for (int j = 0; j < KK - 1; ++j) key[j] = key[j + 1];
      key[KK - 1] = ~0ULL;
    }
    if (lane == 0) wres[w * KK + r] = m;
  }
  __syncthreads();
  if (tid < 64) {                            // final merge of 64 keys
    unsigned long long k = wres[tid];
    #pragma unroll
    for (int r = 0; r < KK; ++r) {
      unsigned long long m = k;
      #pragma unroll
      for (int off = 32; off; off >>= 1) {
        const unsigned long long o = __shfl_xor(m, off, 64);
        m = (o < m) ? o : m;
      }
      if (k == m) k = ~0ULL;                 // consume (keys distinct)
      if (tid == r)
        out[g3 * KK + r] = (float)(unsigned)(m & 0xFFFFFFFFu);
    }
  }
}

// ---- Kernel E: one thread per (query, neighbor); all other outputs ----
__global__ __launch_bounds__(256)
void emit_kernel(const float* __restrict__ positions,
                 float* __restrict__ out)
{
  const int gid = blockIdx.x * 256 + threadIdx.x;    // [0, 262144)
  const size_t g  = (size_t)gid;
  const size_t gq = g >> 4;
  const int b     = (int)(gq >> 12);
  const int qrow  = (int)(gq & 4095);

  const float2* p2 = (const float2*)positions + (size_t)b * LL;
  const int ci = (int)out[g];

  const float2 P = p2[qrow];
  const float2 c = p2[ci];
  const float dx = c.x - P.x;
  const float dy = c.y - P.y;
  const float d2 = __fadd_rn(__fmul_rn(dx, dx), __fmul_rn(dy, dy));

  out[OFF_DIST + g] = bf16r(sqrtf(__fadd_rn(d2, 1e-8f)));
  {
    float2* np_ = (float2*)(out + OFF_NPOS) + g;
    *np_ = make_float2(bf16r(c.x), bf16r(c.y));
  }

  const float SCALE = (float)(3.0 * sqrt(16.0 / M_PI));
  const float PI_F  = (float)M_PI;
  const float tx = dx / SCALE;
  const float ty = dy / SCALE;

  float sxv[NF], cxv[NF], syv[NF], cyv[NF];
  #pragma unroll
  for (int f = 0; f < NF; ++f) {
    const float fr = PI_F * (float)(1 << f);
    sincosf(__fmul_rn(tx, fr), &sxv[f], &cxv[f]);
    sincosf(__fmul_rn(ty, fr), &syv[f], &cyv[f]);
  }
  float4* rp = (float4*)(out + OFF_RPE + g * 64);
  #pragma unroll
  for (int w = 0; w < 4; ++w)
    rp[w]      = make_float4(bf16r(sxv[w*4]), bf16r(sxv[w*4+1]),
                             bf16r(sxv[w*4+2]), bf16r(sxv[w*4+3]));
  #pragma unroll
  for (int w = 0; w < 4; ++w)
    rp[4 + w]  = make_float4(bf16r(cxv[w*4]), bf16r(cxv[w*4+1]),
                             bf16r(cxv[w*4+2]), bf16r(cxv[w*4+3]));
  #pragma unroll
  for (int w = 0; w < 4; ++w)
    rp[8 + w]  = make_float4(bf16r(syv[w*4]), bf16r(syv[w*4+1]),
                             bf16r(syv[w*4+2]), bf16r(syv[w*4+3]));
  #pragma unroll
  for (int w = 0; w < 4; ++w)
    rp[12 + w] = make_float4(bf16r(cyv[w*4]), bf16r(cyv[w*4+1]),
                             bf16r(cyv[w*4+2]), bf16r(cyv[w*4+3]));

  {
    const float v = ((g >> 2) & 1) ? 1.0f : 0.0f;
    float4* sp = (float4*)(out + OFF_SELF) + g;
    *sp = make_float4(v, v, v, v);
  }
}

extern "C" void kernel_launch(void* const* d_in, const int* in_sizes, int n_in,
                              void* d_out, int out_size, void* d_ws, size_t ws_size,
                              hipStream_t stream) {
  const float* positions = (const float*)d_in[0];
  float* out = (float*)d_out;
  unsigned* ws = (unsigned*)d_ws;

  bin_kernel <<<dim3(BB),           dim3(256), 0, stream>>>(positions, ws, out);
  cell_kernel<<<dim3(BB * NCELL),   dim3(256), 0, stream>>>(positions, ws, out);
  hard_kernel<<<dim3(HARD_CAP),     dim3(256), 0, stream>>>(positions, ws, out);
  emit_kernel<<<dim3((int)(N_IDX / 256)), dim3(256), 0, stream>>>(positions, out);
}

// Round 19
// 116.154 us; speedup vs baseline: 1.5077x; 1.5077x over previous
//
#include <hip/hip_runtime.h>
#include <math.h>

// Problem constants (fixed by setup_inputs): B=4, L=4096, k=16, PE_DIM=64.
// d_out is a FLOAT32 buffer; harness bf16-quantizes both sides for compare.
namespace {
constexpr int BB  = 4;
constexpr int LL  = 4096;
constexpr int KK  = 16;
constexpr int GRID = 64;               // 64x64 cells, h=8
constexpr int NCELL = GRID * GRID;     // 4096
constexpr float WORLD_LO = -256.0f, CELL_INV = 0.125f;

// d_ws layout (u32): per batch stride 6208 = cell_start[4097](pad to 4104) +
// sidx u16[4096](2048 u32); then hard_cnt[1] + hard_list[1024]. 103428 B total.
constexpr int WSB_U32   = 6208;
constexpr int SIDX_OFF  = 4104;
constexpr int HARD_CNT  = BB * WSB_U32;      // 24832
constexpr int HARD_LIST = HARD_CNT + 1;
constexpr int HARD_CAP  = 1024;

constexpr size_t N_IDX    = (size_t)BB * LL * KK;                 // 262144
constexpr size_t OFF_RPE  = N_IDX;
constexpr size_t OFF_SELF = OFF_RPE + N_IDX * 64;                 // 17039360
constexpr size_t OFF_DIST = OFF_SELF + (size_t)BB * LL * 64;      // 18087936
constexpr size_t OFF_NPOS = OFF_DIST + N_IDX;                     // 18350080
}

__device__ __forceinline__ float bf16r(float x) {
  unsigned u = __float_as_uint(x);
  unsigned r = (u + 0x7FFFu + ((u >> 16) & 1u)) & 0xFFFF0000u;
  return __uint_as_float(r);
}

// XLA-exact squared distance: rn(dx*dx) + rn(dy*dy), no fma contraction
__device__ __forceinline__ float d2_of(float cx, float cy, float px, float py) {
  const float dx = cx - px, dy = cy - py;
  return __fadd_rn(__fmul_rn(dx, dx), __fmul_rn(dy, dy));
}

// 16-deep predicated bubble insert (static indices only)
__device__ __forceinline__ void insert16(unsigned long long (&key)[KK],
                                         unsigned long long kj) {
  #pragma unroll
  for (int t = 0; t < KK; ++t) {
    const bool lt = kj < key[t];
    const unsigned long long nk = lt ? kj : key[t];
    const unsigned long long ok = lt ? key[t] : kj;
    key[t] = nk; kj = ok;
  }
}

// merge 32 per-lane sorted lists (half-wave); writes 16 results; returns 16th.
__device__ __forceinline__ unsigned long long
merge_write32(unsigned long long (&key)[KK], float* __restrict__ out, size_t g3) {
  unsigned long long last = ~0ULL;
  #pragma unroll
  for (int r = 0; r < KK; ++r) {
    unsigned long long m = key[0];
    #pragma unroll
    for (int off = 16; off; off >>= 1) {
      const unsigned long long o = __shfl_xor(m, off, 32);
      m = (o < m) ? o : m;
    }
    if (key[0] == m) {
      out[g3 * KK + r] = (float)(unsigned)(m & 0xFFFFFFFFu);
      #pragma unroll
      for (int j = 0; j < KK - 1; ++j) key[j] = key[j + 1];
      key[KK - 1] = ~0ULL;
    }
    last = m;
  }
  return last;
}

// ---- Kernel B: counting sort + position reorder (one block/batch; R18-proven) ----
__global__ __launch_bounds__(256)
void bin_kernel(const float* __restrict__ positions,
                unsigned* __restrict__ ws,
                float* __restrict__ out)
{
  __shared__ unsigned cnt[NCELL];            // 16 KB
  __shared__ unsigned wsum[4];
  const int tid = threadIdx.x, b = blockIdx.x;
  const float2* p2 = (const float2*)positions + (size_t)b * LL;
  unsigned* cs = ws + (size_t)b * WSB_U32;
  unsigned short* sidx = (unsigned short*)(cs + SIDX_OFF);
  float2* posw = (float2*)(out + OFF_RPE) + (size_t)b * LL;   // temp stash

  if (b == 0 && tid == 0) ws[HARD_CNT] = 0u;

  #pragma unroll
  for (int j = 0; j < NCELL / 256; ++j) cnt[tid + j * 256] = 0u;
  __syncthreads();

  int cellv[LL / 256];                       // 16 cells/thread, static idx
  #pragma unroll
  for (int j = 0; j < LL / 256; ++j) {
    const int pi = tid + j * 256;
    const float2 p = p2[pi];
    int cx = (int)floorf((p.x - WORLD_LO) * CELL_INV);
    int cy = (int)floorf((p.y - WORLD_LO) * CELL_INV);
    cx = min(max(cx, 0), GRID - 1);
    cy = min(max(cy, 0), GRID - 1);
    cellv[j] = cy * GRID + cx;
    atomicAdd(&cnt[cellv[j]], 1u);
  }
  __syncthreads();

  unsigned csum = 0;                         // 16-cell chunk sum
  #pragma unroll
  for (int k = 0; k < 16; ++k) csum += cnt[tid * 16 + k];
  unsigned inc = csum;                       // wave-64 inclusive scan
  #pragma unroll
  for (int off = 1; off < 64; off <<= 1) {
    const unsigned y = __shfl_up(inc, off, 64);
    if ((tid & 63) >= off) inc += y;
  }
  if ((tid & 63) == 63) wsum[tid >> 6] = inc;
  __syncthreads();
  const int w = tid >> 6;
  const unsigned w0 = wsum[0], w1 = wsum[1], w2 = wsum[2];
  const unsigned woff = (w > 0 ? w0 : 0u) + (w > 1 ? w1 : 0u) + (w > 2 ? w2 : 0u);
  unsigned run = woff + inc - csum;          // exclusive chunk base
  #pragma unroll
  for (int k = 0; k < 16; ++k) {             // in-place: counts -> starts
    const unsigned v = cnt[tid * 16 + k];
    cnt[tid * 16 + k] = run;
    cs[tid * 16 + k] = run;
    run += v;
  }
  if (tid == 255) cs[NCELL] = (unsigned)LL;
  __syncthreads();

  #pragma unroll
  for (int j = 0; j < LL / 256; ++j) {       // scatter idx + position
    const int pi = tid + j * 256;
    const float2 p = p2[pi];
    const unsigned slot = atomicAdd(&cnt[cellv[j]], 1u);
    sidx[slot] = (unsigned short)pi;
    posw[slot] = p;
  }
}

// ---- Kernel Q: half-wave per query; contiguous ring spans from posw ----
__global__ __launch_bounds__(256)
void qsel2_kernel(const float* __restrict__ positions,
                  unsigned* __restrict__ ws,
                  float* __restrict__ out)
{
  const int tid  = threadIdx.x;
  const int b    = blockIdx.x >> 9, brow = blockIdx.x & 511;
  const int q    = tid >> 5, s = tid & 31;
  const int qrow = brow * 8 + q;

  const float2* p2 = (const float2*)positions + (size_t)b * LL;
  unsigned* cs = ws + (size_t)b * WSB_U32;
  const unsigned short* sidx = (const unsigned short*)(cs + SIDX_OFF);
  const float2* posw = (const float2*)(out + OFF_RPE) + (size_t)b * LL;
  const float2 P = p2[qrow];
  const size_t g3 = (size_t)b * LL + qrow;

  const float r2 = __fadd_rn(__fmul_rn(P.x, P.x), __fmul_rn(P.y, P.y));

  // analytic ring radius (R16-validated): disk for E[cnt]=40, far -> hard
  bool needhard = (r2 > 19321.0f);
  int Rs = 1;
  if (!needhard) {
    const float rho = 6.99f * __expf(r2 * 1.0e-4f);
    Rs = (int)ceilf(rho * 0.125f + 0.5f);
    if (Rs < 1) Rs = 1;
    if (Rs > 6) needhard = true;
  }

  if (!needhard) {
    const int cx = min(max((int)floorf((P.x - WORLD_LO) * CELL_INV), 0), GRID - 1);
    const int cy = min(max((int)floorf((P.y - WORLD_LO) * CELL_INV), 0), GRID - 1);
    unsigned long long key[KK];
    #pragma unroll
    for (int j = 0; j < KK; ++j) key[j] = ~0ULL;
    const int ry0 = max(cy - Rs, 0), ry1 = min(cy + Rs, GRID - 1);
    const int rx0 = max(cx - Rs, 0), rx1 = min(cx + Rs, GRID - 1);
    for (int row = ry0; row <= ry1; ++row) {       // contiguous span per row
      const unsigned a = cs[row * GRID + rx0];
      const unsigned e = cs[row * GRID + rx1 + 1];
      for (unsigned j = a + (unsigned)s; j < e; j += 32u) {
        const float2 c = posw[j];                  // coalesced (sorted)
        const float d2 = d2_of(c.x, c.y, P.x, P.y);
        const int ci = (int)sidx[j];               // coalesced u16
        if (ci != qrow) {
          const unsigned long long kj =
              ((unsigned long long)__float_as_uint(d2) << 32) | (unsigned)ci;
          if (kj < key[KK - 1]) insert16(key, kj);
        }
      }
    }
    const unsigned long long kth = merge_write32(key, out, g3);
    const float kd = __uint_as_float((unsigned)(kth >> 32));
    const float bound = (float)(Rs * 8 * Rs * 8);
    // certified: unexplored cells all >= Rs*8 away -> d2 >= bound > kth.
    // (clamped out-of-world points lie beyond their edge cells: bound holds)
    needhard = !(kd < bound);
  }

  if (needhard) {
    unsigned slot = 0;
    if (s == 0) slot = atomicAdd(&ws[HARD_CNT], 1u);
    slot = __shfl(slot, 0, 32);
    if (s == 0 && slot < (unsigned)HARD_CAP)
      ws[HARD_LIST + slot] = ((unsigned)b << 12) | (unsigned)qrow;
    if (slot >= (unsigned)HARD_CAP) {
      // overflow (p~0): inline exhaustive, half-wave (R16-proven)
      unsigned long long key[KK];
      #pragma unroll
      for (int j = 0; j < KK; ++j) key[j] = ~0ULL;
      unsigned dmax = 0xFFFFFFFFu;
      for (int i = 0; i < LL / 32; ++i) {
        const int ci = s + i * 32;
        const float2 c = p2[ci];
        const float d2 = d2_of(c.x, c.y, P.x, P.y);
        const unsigned d2b = __float_as_uint(d2);
        if (d2b < dmax && ci != qrow) {
          insert16(key, ((unsigned long long)d2b << 32) | (unsigned)ci);
          dmax = (unsigned)(key[KK - 1] >> 32);
        }
      }
      merge_write32(key, out, g3);
    }
  }
}

// ---- Kernel H: one block per hard query; exhaustive exact top-16 (R18) ----
__global__ __launch_bounds__(256)
void hard_kernel(const float* __restrict__ positions,
                 const unsigned* __restrict__ ws,
                 float* __restrict__ out)
{
  __shared__ unsigned long long wres[4 * KK];
  const unsigned cntr = ws[HARD_CNT];
  const unsigned n = cntr < (unsigned)HARD_CAP ? cntr : (unsigned)HARD_CAP;
  if (blockIdx.x >= n) return;
  const unsigned enc = ws[HARD_LIST + blockIdx.x];
  const int b = (int)(enc >> 12), qrow = (int)(enc & 4095);
  const float2* p2 = (const float2*)positions + (size_t)b * LL;
  const float2 P = p2[qrow];
  const int tid = threadIdx.x, w = tid >> 6, lane = tid & 63;
  const size_t g3 = (size_t)b * LL + qrow;

  unsigned long long key[KK];
  #pragma unroll
  for (int j = 0; j < KK; ++j) key[j] = ~0ULL;
  #pragma unroll
  for (int i = 0; i < KK; ++i) {             // 16 coalesced candidates/thread
    const int ci = tid + i * 256;
    const float2 c = p2[ci];
    const float d2 = d2_of(c.x, c.y, P.x, P.y);
    if (ci != qrow)
      insert16(key, ((unsigned long long)__float_as_uint(d2) << 32) |
                    (unsigned)ci);
  }
  #pragma unroll
  for (int r = 0; r < KK; ++r) {             // per-wave width-64 merge
    unsigned long long m = key[0];
    #pragma unroll
    for (int off = 32; off; off >>= 1) {
      const unsigned long long o = __shfl_xor(m, off, 64);
      m = (o < m) ? o : m;
    }
    if (key[0] == m) {
      #pragma unroll
      for (int j = 0; j < KK - 1; ++j) key[j] = key[j + 1];
      key[KK - 1] = ~0ULL;
    }
    if (lane == 0) wres[w * KK + r] = m;
  }
  __syncthreads();
  if (tid < 64) {                            // final merge of 64 keys
    unsigned long long k = wres[tid];
    #pragma unroll
    for (int r = 0; r < KK; ++r) {
      unsigned long long m = k;
      #pragma unroll
      for (int off = 32; off; off >>= 1) {
        const unsigned long long o = __shfl_xor(m, off, 64);
        m = (o < m) ? o : m;
      }
      if (k == m) k = ~0ULL;
      if (tid == r)
        out[g3 * KK + r] = (float)(unsigned)(m & 0xFFFFFFFFu);
    }
  }
}

// ---- Kernel E: 16 threads per (query, neighbor) -> 2 sincosf each ----
__global__ __launch_bounds__(256)
void emit_kernel(const float* __restrict__ positions,
                 float* __restrict__ out)
{
  const unsigned gid = blockIdx.x * 256 + threadIdx.x;  // [0, 4194304)
  const size_t g = (size_t)(gid >> 4);                  // (query, neighbor)
  const int f = (int)(gid & 15);                        // frequency index
  const size_t gq = g >> 4;
  const int r = (int)(g & 15);
  const int b = (int)(gq >> 12);
  const int qrow = (int)(gq & 4095);

  const float2* p2 = (const float2*)positions + (size_t)b * LL;
  const int ci = (int)out[g];                // idx (final after hard_kernel)

  const float2 P = p2[qrow];
  const float2 c = p2[ci];
  const float dx = c.x - P.x;
  const float dy = c.y - P.y;

  const float SCALE = (float)(3.0 * sqrt(16.0 / M_PI));
  const float PI_F  = (float)M_PI;
  const float tx = dx / SCALE;
  const float ty = dy / SCALE;
  const float fr = PI_F * (float)(1 << f);

  float sx, cx_, sy, cy_;
  sincosf(__fmul_rn(tx, fr), &sx, &cx_);     // accurate ocml sincos
  sincosf(__fmul_rn(ty, fr), &sy, &cy_);

  const size_t base = OFF_RPE + g * 64;
  out[base +      f] = bf16r(sx);
  out[base + 16 + f] = bf16r(cx_);
  out[base + 32 + f] = bf16r(sy);
  out[base + 48 + f] = bf16r(cy_);

  if (f == 0) {
    const float d2 = __fadd_rn(__fmul_rn(dx, dx), __fmul_rn(dy, dy));
    out[OFF_DIST + g] = bf16r(sqrtf(__fadd_rn(d2, 1e-8f)));
  } else if (f == 1) {
    float2* np_ = (float2*)(out + OFF_NPOS) + g;
    *np_ = make_float2(bf16r(c.x), bf16r(c.y));
  }
  if (r == 0) {                              // self_rpe: 4 floats per f-thread
    const float v = ((f >> 2) & 1) ? 1.0f : 0.0f;
    float4* sp = (float4*)(out + OFF_SELF) + gq * 16 + f;
    *sp = make_float4(v, v, v, v);
  }
}

extern "C" void kernel_launch(void* const* d_in, const int* in_sizes, int n_in,
                              void* d_out, int out_size, void* d_ws, size_t ws_size,
                              hipStream_t stream) {
  const float* positions = (const float*)d_in[0];
  float* out = (float*)d_out;
  unsigned* ws = (unsigned*)d_ws;

  bin_kernel  <<<dim3(BB),            dim3(256), 0, stream>>>(positions, ws, out);
  qsel2_kernel<<<dim3(BB * (LL / 8)), dim3(256), 0, stream>>>(positions, ws, out);
  hard_kernel <<<dim3(HARD_CAP),      dim3(256), 0, stream>>>(positions, ws, out);
  emit_kernel <<<dim3((int)(N_IDX * 16 / 256)), dim3(256), 0, stream>>>(positions, out);
}

// Round 20
// 84.941 us; speedup vs baseline: 2.0617x; 1.3675x over previous
//
#include <hip/hip_runtime.h>
#include <math.h>

// Problem constants (fixed by setup_inputs): B=4, L=4096, k=16, PE_DIM=64.
// d_out is a FLOAT32 buffer; harness bf16-quantizes both sides for compare.
namespace {
constexpr int BB  = 4;
constexpr int LL  = 4096;
constexpr int KK  = 16;
constexpr int GRID = 64;               // 64x64 cells, h=8
constexpr int NCELL = GRID * GRID;     // 4096
constexpr float WORLD_LO = -256.0f, CELL_INV = 0.125f;

// d_ws layout (u32): per batch stride 6208 = cell_start[4097](pad 4104) +
// sidx u16[4096](2048 u32); then hard_cnt[1] + hard_list[1024]. 103428 B.
constexpr int WSB_U32   = 6208;
constexpr int SIDX_OFF  = 4104;
constexpr int HARD_CNT  = BB * WSB_U32;      // 24832
constexpr int HARD_LIST = HARD_CNT + 1;
constexpr int HARD_CAP  = 1024;

constexpr size_t N_IDX    = (size_t)BB * LL * KK;                 // 262144
constexpr size_t OFF_RPE  = N_IDX;
constexpr size_t OFF_SELF = OFF_RPE + N_IDX * 64;                 // 17039360
constexpr size_t OFF_DIST = OFF_SELF + (size_t)BB * LL * 64;      // 18087936
constexpr size_t OFF_NPOS = OFF_DIST + N_IDX;                     // 18350080
}

__device__ __forceinline__ float bf16r(float x) {
  unsigned u = __float_as_uint(x);
  unsigned r = (u + 0x7FFFu + ((u >> 16) & 1u)) & 0xFFFF0000u;
  return __uint_as_float(r);
}

// XLA-exact squared distance: rn(dx*dx) + rn(dy*dy), no fma contraction
__device__ __forceinline__ float d2_of(float cx, float cy, float px, float py) {
  const float dx = cx - px, dy = cy - py;
  return __fadd_rn(__fmul_rn(dx, dx), __fmul_rn(dy, dy));
}

// 16-deep predicated bubble insert (static indices only) — hard paths only
__device__ __forceinline__ void insert16(unsigned long long (&key)[KK],
                                         unsigned long long kj) {
  #pragma unroll
  for (int t = 0; t < KK; ++t) {
    const bool lt = kj < key[t];
    const unsigned long long nk = lt ? kj : key[t];
    const unsigned long long ok = lt ? key[t] : kj;
    key[t] = nk; kj = ok;
  }
}

// position of the n-th (0-based) set bit of m; n < popcll(m) assumed
__device__ __forceinline__ int nth_set(unsigned long long m, int n) {
  int src = 0;
  #pragma unroll
  for (int w = 32; w >= 1; w >>= 1) {
    const unsigned long long lowm = (w == 64) ? ~0ull : ((1ull << w) - 1ull);
    const int c = __popcll(m & lowm);
    const bool go = n >= c;
    n   -= go ? c : 0;
    m    = go ? (m >> w) : m;
    src += go ? w : 0;
  }
  return src;
}

// full bitonic sort of 64 u64 keys across the wave (ascending by lane)
__device__ __forceinline__ unsigned long long
bitonic64(unsigned long long key, int lane) {
  #pragma unroll
  for (int k = 2; k <= 64; k <<= 1) {
    #pragma unroll
    for (int j = k >> 1; j >= 1; j >>= 1) {
      const unsigned long long o = __shfl_xor(key, j, 64);
      const bool takeMin = (((lane & j) == 0) == ((lane & k) == 0));
      const bool less = key < o;
      key = (takeMin == less) ? key : o;
    }
  }
  return key;
}

// ---- Kernel B: counting sort + position reorder (one block/batch; proven) ----
__global__ __launch_bounds__(256)
void bin_kernel(const float* __restrict__ positions,
                unsigned* __restrict__ ws,
                float* __restrict__ out)
{
  __shared__ unsigned cnt[NCELL];            // 16 KB
  __shared__ unsigned wsum[4];
  const int tid = threadIdx.x, b = blockIdx.x;
  const float2* p2 = (const float2*)positions + (size_t)b * LL;
  unsigned* cs = ws + (size_t)b * WSB_U32;
  unsigned short* sidx = (unsigned short*)(cs + SIDX_OFF);
  float2* posw = (float2*)(out + OFF_RPE) + (size_t)b * LL;   // temp stash

  if (b == 0 && tid == 0) ws[HARD_CNT] = 0u;

  #pragma unroll
  for (int j = 0; j < NCELL / 256; ++j) cnt[tid + j * 256] = 0u;
  __syncthreads();

  int cellv[LL / 256];                       // 16 cells/thread, static idx
  #pragma unroll
  for (int j = 0; j < LL / 256; ++j) {
    const int pi = tid + j * 256;
    const float2 p = p2[pi];
    int cx = (int)floorf((p.x - WORLD_LO) * CELL_INV);
    int cy = (int)floorf((p.y - WORLD_LO) * CELL_INV);
    cx = min(max(cx, 0), GRID - 1);
    cy = min(max(cy, 0), GRID - 1);
    cellv[j] = cy * GRID + cx;
    atomicAdd(&cnt[cellv[j]], 1u);
  }
  __syncthreads();

  unsigned csum = 0;                         // 16-cell chunk sum
  #pragma unroll
  for (int k = 0; k < 16; ++k) csum += cnt[tid * 16 + k];
  unsigned inc = csum;                       // wave-64 inclusive scan
  #pragma unroll
  for (int off = 1; off < 64; off <<= 1) {
    const unsigned y = __shfl_up(inc, off, 64);
    if ((tid & 63) >= off) inc += y;
  }
  if ((tid & 63) == 63) wsum[tid >> 6] = inc;
  __syncthreads();
  const int w = tid >> 6;
  const unsigned w0 = wsum[0], w1 = wsum[1], w2 = wsum[2];
  const unsigned woff = (w > 0 ? w0 : 0u) + (w > 1 ? w1 : 0u) + (w > 2 ? w2 : 0u);
  unsigned run = woff + inc - csum;          // exclusive chunk base
  #pragma unroll
  for (int k = 0; k < 16; ++k) {             // in-place: counts -> starts
    const unsigned v = cnt[tid * 16 + k];
    cnt[tid * 16 + k] = run;
    cs[tid * 16 + k] = run;
    run += v;
  }
  if (tid == 255) cs[NCELL] = (unsigned)LL;
  __syncthreads();

  #pragma unroll
  for (int j = 0; j < LL / 256; ++j) {       // scatter idx + position
    const int pi = tid + j * 256;
    const float2 p = p2[pi];
    const unsigned slot = atomicAdd(&cnt[cellv[j]], 1u);
    sidx[slot] = (unsigned short)pi;
    posw[slot] = p;
  }
}

// ---- Kernel Q: one WAVE per query; tau-filter + lane-compact + bitonic ----
__global__ __launch_bounds__(256)
void qsel3_kernel(const float* __restrict__ positions,
                  unsigned* __restrict__ ws,
                  float* __restrict__ out)
{
  const int tid  = threadIdx.x;
  const int b    = blockIdx.x >> 10, brow = blockIdx.x & 1023;
  const int w    = tid >> 6, lane = tid & 63;
  const int qrow = brow * 4 + w;

  const float2* p2 = (const float2*)positions + (size_t)b * LL;
  unsigned* cs = ws + (size_t)b * WSB_U32;
  const unsigned short* sidx = (const unsigned short*)(cs + SIDX_OFF);
  const float2* posw = (const float2*)(out + OFF_RPE) + (size_t)b * LL;
  const float2 P = p2[qrow];
  const size_t g3 = (size_t)b * LL + qrow;

  const float r2 = __fadd_rn(__fmul_rn(P.x, P.x), __fmul_rn(P.y, P.y));

  // analytic disk (E[cnt]=40, R16-validated): rho = 6.99 e^(r^2*1e-4)
  bool needhard = (r2 > 19321.0f);
  int Rs = 1; float tau = 0.0f;
  if (!needhard) {
    const float rho = 6.99f * __expf(r2 * 1.0e-4f);
    tau = rho * rho;
    Rs = (int)ceilf(rho * 0.125f + 0.5f);
    if (Rs < 1) Rs = 1;
    if (Rs > 6) needhard = true;
  }

  if (!needhard) {
    const int cx = min(max((int)floorf((P.x - WORLD_LO) * CELL_INV), 0), GRID - 1);
    const int cy = min(max((int)floorf((P.y - WORLD_LO) * CELL_INV), 0), GRID - 1);
    const int ry0 = max(cy - Rs, 0), ry1 = min(cy + Rs, GRID - 1);
    const int rx0 = max(cx - Rs, 0), rx1 = min(cx + Rs, GRID - 1);

    // collect: tau-passing candidates, compacted one-per-lane
    unsigned off = 0;
    float cd2 = 0.0f; int cidx = 0; bool have = false;
    for (int row = ry0; row <= ry1; ++row) {
      const unsigned a = cs[row * GRID + rx0];
      const unsigned e = cs[row * GRID + rx1 + 1];
      for (unsigned c0 = a; c0 < e; c0 += 64u) {
        const unsigned j = c0 + (unsigned)lane;
        const bool inr = j < e;
        float d2 = 1e30f; int ci = -1;
        if (inr) {
          const float2 c = posw[j];            // coalesced (cell-sorted)
          d2 = d2_of(c.x, c.y, P.x, P.y);
          ci = (int)sidx[j];
        }
        const bool pr = inr && (d2 <= tau) && (ci != qrow);
        const unsigned long long bal = __ballot(pr);
        const int cnt = __popcll(bal);
        const int want = lane - (int)off;
        const int wc = min(max(want, 0), 63);
        const int src = nth_set(bal, wc);      // all lanes compute (uniform flow)
        const float rd2 = __shfl(d2, src, 64);
        const int   rci = __shfl(ci, src, 64);
        if (want >= 0 && want < cnt) { cd2 = rd2; cidx = rci; have = true; }
        off += (unsigned)cnt;
      }
    }

    if (off <= 64u) {
      unsigned long long key = have
          ? (((unsigned long long)__float_as_uint(cd2) << 32) | (unsigned)cidx)
          : ~0ULL;
      key = bitonic64(key, lane);              // lane i = rank i
      const unsigned long long kth = __shfl(key, 15, 64);
      const float kd = __uint_as_float((unsigned)(kth >> 32));
      const float bound = (float)(Rs * 8 * Rs * 8);
      // certified: unexplored cells >= Rs*8 away; tau-excluded > tau >= kth
      if (kd < bound) {
        if (lane < KK)
          out[g3 * KK + lane] = (float)(unsigned)(key & 0xFFFFFFFFu);
      } else needhard = true;
    } else needhard = true;                    // >64 passing: cap overflow
  }

  if (needhard) {
    unsigned slot = 0;
    if (lane == 0) slot = atomicAdd(&ws[HARD_CNT], 1u);
    slot = __shfl(slot, 0, 64);
    if (lane == 0 && slot < (unsigned)HARD_CAP)
      ws[HARD_LIST + slot] = ((unsigned)b << 12) | (unsigned)qrow;
    if (slot >= (unsigned)HARD_CAP) {
      // overflow (p~0): inline exhaustive, full wave
      unsigned long long key[KK];
      #pragma unroll
      for (int j = 0; j < KK; ++j) key[j] = ~0ULL;
      unsigned dmax = 0xFFFFFFFFu;
      for (int i = 0; i < LL / 64; ++i) {
        const int ci = lane + i * 64;
        const float2 c = p2[ci];
        const float d2 = d2_of(c.x, c.y, P.x, P.y);
        const unsigned d2b = __float_as_uint(d2);
        if (d2b < dmax && ci != qrow) {
          insert16(key, ((unsigned long long)d2b << 32) | (unsigned)ci);
          dmax = (unsigned)(key[KK - 1] >> 32);
        }
      }
      #pragma unroll
      for (int r = 0; r < KK; ++r) {           // width-64 min + winner-pop
        unsigned long long m = key[0];
        #pragma unroll
        for (int o2 = 32; o2; o2 >>= 1) {
          const unsigned long long o = __shfl_xor(m, o2, 64);
          m = (o < m) ? o : m;
        }
        if (key[0] == m) {
          out[g3 * KK + r] = (float)(unsigned)(m & 0xFFFFFFFFu);
          #pragma unroll
          for (int j = 0; j < KK - 1; ++j) key[j] = key[j + 1];
          key[KK - 1] = ~0ULL;
        }
      }
    }
  }
}

// ---- Kernel H: one block per hard query; exhaustive exact top-16 (proven) ----
__global__ __launch_bounds__(256)
void hard_kernel(const float* __restrict__ positions,
                 const unsigned* __restrict__ ws,
                 float* __restrict__ out)
{
  __shared__ unsigned long long wres[4 * KK];
  const unsigned cntr = ws[HARD_CNT];
  const unsigned n = cntr < (unsigned)HARD_CAP ? cntr : (unsigned)HARD_CAP;
  if (blockIdx.x >= n) return;
  const unsigned enc = ws[HARD_LIST + blockIdx.x];
  const int b = (int)(enc >> 12), qrow = (int)(enc & 4095);
  const float2* p2 = (const float2*)positions + (size_t)b * LL;
  const float2 P = p2[qrow];
  const int tid = threadIdx.x, w = tid >> 6, lane = tid & 63;
  const size_t g3 = (size_t)b * LL + qrow;

  unsigned long long key[KK];
  #pragma unroll
  for (int j = 0; j < KK; ++j) key[j] = ~0ULL;
  #pragma unroll
  for (int i = 0; i < KK; ++i) {             // 16 coalesced candidates/thread
    const int ci = tid + i * 256;
    const float2 c = p2[ci];
    const float d2 = d2_of(c.x, c.y, P.x, P.y);
    if (ci != qrow)
      insert16(key, ((unsigned long long)__float_as_uint(d2) << 32) |
                    (unsigned)ci);
  }
  #pragma unroll
  for (int r = 0; r < KK; ++r) {             // per-wave width-64 merge
    unsigned long long m = key[0];
    #pragma unroll
    for (int off = 32; off; off >>= 1) {
      const unsigned long long o = __shfl_xor(m, off, 64);
      m = (o < m) ? o : m;
    }
    if (key[0] == m) {
      #pragma unroll
      for (int j = 0; j < KK - 1; ++j) key[j] = key[j + 1];
      key[KK - 1] = ~0ULL;
    }
    if (lane == 0) wres[w * KK + r] = m;
  }
  __syncthreads();
  if (tid < 64) {                            // final merge of 64 keys
    unsigned long long k = wres[tid];
    #pragma unroll
    for (int r = 0; r < KK; ++r) {
      unsigned long long m = k;
      #pragma unroll
      for (int off = 32; off; off >>= 1) {
        const unsigned long long o = __shfl_xor(m, off, 64);
        m = (o < m) ? o : m;
      }
      if (k == m) k = ~0ULL;
      if (tid == r)
        out[g3 * KK + r] = (float)(unsigned)(m & 0xFFFFFFFFu);
    }
  }
}

// ---- Kernel E: 16 threads per (query, neighbor) -> 2 sincosf each ----
__global__ __launch_bounds__(256)
void emit_kernel(const float* __restrict__ positions,
                 float* __restrict__ out)
{
  const unsigned gid = blockIdx.x * 256 + threadIdx.x;  // [0, 4194304)
  const size_t g = (size_t)(gid >> 4);                  // (query, neighbor)
  const int f = (int)(gid & 15);                        // frequency index
  const size_t gq = g >> 4;
  const int r = (int)(g & 15);
  const int b = (int)(gq >> 12);
  const int qrow = (int)(gq & 4095);

  const float2* p2 = (const float2*)positions + (size_t)b * LL;
  const int ci = (int)out[g];                // idx (final after hard_kernel)

  const float2 P = p2[qrow];
  const float2 c = p2[ci];
  const float dx = c.x - P.x;
  const float dy = c.y - P.y;

  const float SCALE = (float)(3.0 * sqrt(16.0 / M_PI));
  const float PI_F  = (float)M_PI;
  const float tx = dx / SCALE;
  const float ty = dy / SCALE;
  const float fr = PI_F * (float)(1 << f);

  float sx, cx_, sy, cy_;
  sincosf(__fmul_rn(tx, fr), &sx, &cx_);     // accurate ocml sincos
  sincosf(__fmul_rn(ty, fr), &sy, &cy_);

  const size_t base = OFF_RPE + g * 64;
  out[base +      f] = bf16r(sx);
  out[base + 16 + f] = bf16r(cx_);
  out[base + 32 + f] = bf16r(sy);
  out[base + 48 + f] = bf16r(cy_);

  if (f == 0) {
    const float d2 = __fadd_rn(__fmul_rn(dx, dx), __fmul_rn(dy, dy));
    out[OFF_DIST + g] = bf16r(sqrtf(__fadd_rn(d2, 1e-8f)));
  } else if (f == 1) {
    float2* np_ = (float2*)(out + OFF_NPOS) + g;
    *np_ = make_float2(bf16r(c.x), bf16r(c.y));
  }
  if (r == 0) {                              // self_rpe: 4 floats per f-thread
    const float v = ((f >> 2) & 1) ? 1.0f : 0.0f;
    float4* sp = (float4*)(out + OFF_SELF) + gq * 16 + f;
    *sp = make_float4(v, v, v, v);
  }
}

extern "C" void kernel_launch(void* const* d_in, const int* in_sizes, int n_in,
                              void* d_out, int out_size, void* d_ws, size_t ws_size,
                              hipStream_t stream) {
  const float* positions = (const float*)d_in[0];
  float* out = (float*)d_out;
  unsigned* ws = (unsigned*)d_ws;

  bin_kernel  <<<dim3(BB),            dim3(256), 0, stream>>>(positions, ws, out);
  qsel3_kernel<<<dim3(BB * (LL / 4)), dim3(256), 0, stream>>>(positions, ws, out);
  hard_kernel <<<dim3(HARD_CAP),      dim3(256), 0, stream>>>(positions, ws, out);
  emit_kernel <<<dim3((int)(N_IDX * 16 / 256)), dim3(256), 0, stream>>>(positions, out);
}